// Round 9
// baseline (226.689 us; speedup 1.0000x reference)
//
#include <hip/hip_runtime.h>
#include <math.h>

#define B_ 2
#define T_ 2048
#define D_ 1024
#define H_ 16
#define DK 64
#define BH_ (B_*H_)

typedef __attribute__((ext_vector_type(8))) short short8;   // 8 bf16 = 4 VGPRs
typedef __attribute__((ext_vector_type(4))) float fragC;    // MFMA C/D

#define MFMA32(A,B,C) __builtin_amdgcn_mfma_f32_16x16x32_bf16((A),(B),(C),0,0,0)

#if defined(__HIP_DEVICE_COMPILE__) && __has_builtin(__builtin_amdgcn_exp2f)
#define EXP2 __builtin_amdgcn_exp2f
#else
#define EXP2 exp2f
#endif

__device__ __forceinline__ unsigned short f2bf(float x) {
    union { float f; unsigned u; } c; c.f = x;
    unsigned r = c.u + 0x7fff + ((c.u >> 16) & 1);   // RNE
    return (unsigned short)(r >> 16);
}

__device__ __forceinline__ unsigned pack2bf(float a, float b) {
    return (unsigned)f2bf(a) | ((unsigned)f2bf(b) << 16);
}

// truncating bf16 pair-pack in ONE op: bytes [a.2,a.3,b.2,b.3]
__device__ __forceinline__ unsigned permpack(float a, float b) {
    union { float f; unsigned u; } ca, cb; ca.f = a; cb.f = b;
    return __builtin_amdgcn_perm(cb.u, ca.u, 0x07060302);
}

// truncate float to bf16-representable value (matches permpack semantics)
__device__ __forceinline__ float truncbf(float x) {
    union { float f; unsigned u; } c; c.f = x;
    c.u &= 0xffff0000u;
    return c.f;
}

__device__ __forceinline__ short8 packbf8(float4 a, float4 b) {
    union { short8 v; unsigned u[4]; } r;
    r.u[0] = pack2bf(a.x, a.y); r.u[1] = pack2bf(a.z, a.w);
    r.u[2] = pack2bf(b.x, b.y); r.u[3] = pack2bf(b.z, b.w);
    return r.v;
}

// async global->LDS, 16B per lane
__device__ __forceinline__ void gload_lds16(const void* g, void* l) {
    __builtin_amdgcn_global_load_lds(
        (const __attribute__((address_space(1))) unsigned int*)g,
        (__attribute__((address_space(3))) unsigned int*)l, 16, 0, 0);
}

// ---------------------------------------------------------------------------
// Kernel 1: MFMA QKV projection + in-kernel weight conversion.  (R5 verbatim)
// ---------------------------------------------------------------------------
__global__ __launch_bounds__(256) void qkv_kernel(
    const float* __restrict__ x,
    const float* __restrict__ Wq, const float* __restrict__ Wk,
    const float* __restrict__ Wv, const float* __restrict__ Wp,
    unsigned short* __restrict__ Wb,
    unsigned short* __restrict__ q, unsigned short* __restrict__ k,
    unsigned short* __restrict__ vt)
{
    __shared__ unsigned short Wl[3*64*64];       // [mat][out][d]

    const int bh = blockIdx.x;
    const int b  = bh >> 4, h = bh & 15;
    const int t0 = blockIdx.y * 128;
    const int tid = threadIdx.x;
    const int wave = tid >> 6, lane = tid & 63;
    const int n = lane & 15, quad = lane >> 4;

    // Wp side job: block L converts floats [L*2048, L*2048+2048)
    {
        const int L = bh + (blockIdx.y << 5);                 // 0..511
        const float* src = Wp + (size_t)L*2048 + tid*8;
        float4 a = *(const float4*)src;
        float4 b2 = *(const float4*)(src + 4);
        *(uint4*)(Wb + (size_t)L*2048 + tid*8) =
            make_uint4(pack2bf(a.x, a.y), pack2bf(a.z, a.w),
                       pack2bf(b2.x, b2.y), pack2bf(b2.z, b2.w));
    }

    // convert this head's 3x64x64 fp32 weights -> LDS bf16
    #pragma unroll
    for (int mat = 0; mat < 3; ++mat) {
        const float* ws = ((mat == 0) ? Wq : (mat == 1) ? Wk : Wv)
                          + (size_t)h * 4096;
        #pragma unroll
        for (int j = 0; j < 2; ++j) {
            const int e = (j*256 + tid) * 8;
            float4 a = *(const float4*)&ws[e];
            float4 b2 = *(const float4*)&ws[e + 4];
            *(uint4*)&Wl[mat*4096 + e] =
                make_uint4(pack2bf(a.x, a.y), pack2bf(a.z, a.w),
                           pack2bf(b2.x, b2.y), pack2bf(b2.z, b2.w));
        }
    }

    // x fragments: fp32 loads + RNE pack (lane n <-> t = tw + rt*16 + n)
    const int tw = t0 + wave*32;
    short8 xf[2][2];
    #pragma unroll
    for (int rt = 0; rt < 2; ++rt) {
        const float* xr = &x[((size_t)b*T_ + tw + rt*16 + n)*D_ + h*DK];
        float4 a0 = *(const float4*)&xr[quad*8];
        float4 a1 = *(const float4*)&xr[quad*8 + 4];
        xf[rt][0] = packbf8(a0, a1);
        float4 b0 = *(const float4*)&xr[32 + quad*8];
        float4 b1 = *(const float4*)&xr[32 + quad*8 + 4];
        xf[rt][1] = packbf8(b0, b1);
    }
    __syncthreads();

    const float qsc = 0.125f * 1.44269504088896340736f;
    const int tb0 = blockIdx.y*8 + wave*2;       // tiled t16-block base
    #pragma unroll
    for (int mat = 0; mat < 3; ++mat) {
        const int wbase = mat * 4096;
        #pragma unroll
        for (int ct = 0; ct < 4; ++ct) {
            short8 wf0 = *(const short8*)&Wl[wbase + (ct*16 + n)*64 + quad*8];
            short8 wf1 = *(const short8*)&Wl[wbase + (ct*16 + n)*64 + 32 + quad*8];
            if (mat < 2) {
                #pragma unroll
                for (int rt = 0; rt < 2; ++rt) {
                    fragC z = {0.f,0.f,0.f,0.f};
                    // q^T/k^T: C col = t = n, row = out = ct*16+quad*4+r
                    z = MFMA32(wf0, xf[rt][0], z);
                    z = MFMA32(wf1, xf[rt][1], z);
                    if (mat == 0) {
                        z[0] *= qsc; z[1] *= qsc; z[2] *= qsc; z[3] *= qsc;
                    }
                    unsigned short* dstg = (mat == 0) ? q : k;
                    unsigned short* dp = &dstg[((size_t)bh*128 + tb0 + rt)*1024
                                               + (ct*2 + (quad>>1))*128 + n*8 + (quad&1)*4];
                    *(uint2*)dp = make_uint2(pack2bf(z[0], z[1]), pack2bf(z[2], z[3]));
                }
            } else {
                // v: C col = d = ct*16+n, row = t = quad*4+r; rt pair -> one uint4
                uint4 pv4;
                {
                    fragC z = {0.f,0.f,0.f,0.f};
                    z = MFMA32(xf[0][0], wf0, z);
                    z = MFMA32(xf[0][1], wf1, z);
                    pv4.x = pack2bf(z[0], z[1]); pv4.y = pack2bf(z[2], z[3]);
                }
                {
                    fragC z = {0.f,0.f,0.f,0.f};
                    z = MFMA32(xf[1][0], wf0, z);
                    z = MFMA32(xf[1][1], wf1, z);
                    pv4.z = pack2bf(z[0], z[1]); pv4.w = pack2bf(z[2], z[3]);
                }
                const int ktv = tw >> 6, pv = (tw >> 5) & 1;
                unsigned short* dp = &vt[(size_t)bh*131072 + ktv*4096
                                         + ct*1024 + pv*512 + lane*8];
                *(uint4*)dp = pv4;
            }
        }
    }
}

// ---------------------------------------------------------------------------
// Kernel 2: causal flash attention — R9: R5's key-split register-resident
// structure + K DOUBLE-BUFFER via MACRO expansion (R8 post-mortem: the
// lambda's reference-parameter arrays took addresses -> scratch -> 252MB
// spill writes.  Macros = zero address-taking, every index compile-time).
// kfA/kfB alternate in a 2-unrolled pair loop: each K load gets ~1.2 tiles
// (~1300 cyc) of flight vs R5's ~250 cyc (the one exposed load in R5).
// Persistent live: o64+qf32+kfA32+kfB32+vv32+lsc4 ~ 196 (+~24 transient)
// < 256 cap of launch_bounds(256,2).  NEVER tighten the cap (R7).
// Block = (bh, qt) = 64 queries; 4 waves split KEY tiles (kt = w, w+4, ..):
// serial path 8 tiles, zero per-tile barriers; V(t+4) issued at tile end
// (full-tile flight).  One barrier: 64KB-LDS cross-wave O/l combine.
// Grid swizzle: XCD id&7 owns bh 4x..4x+3; qt map {31-g, g, 23-g, 8+g}.
// ---------------------------------------------------------------------------

#define LOADK(KF, TT)                                                        \
    _Pragma("unroll")                                                        \
    for (int ct = 0; ct < 4; ++ct) {                                         \
        KF[ct][0] = *(const short8*)&kg[(size_t)(TT)*4096 + ct*1024];        \
        KF[ct][1] = *(const short8*)&kg[(size_t)(TT)*4096 + ct*1024 + 512];  \
    }

#define LOADV(TT)                                                            \
    _Pragma("unroll")                                                        \
    for (int dt = 0; dt < 4; ++dt) {                                         \
        vv[dt][0] = *(const short8*)&vg[(size_t)(TT)*4096 + dt*1024];        \
        vv[dt][1] = *(const short8*)&vg[(size_t)(TT)*4096 + dt*1024 + 512];  \
    }

#define SMAX(CV, CT, CP, SL)                                                 \
    {                                                                        \
        float p0 = EXP2(CV[0]), p1 = EXP2(CV[1]);                            \
        float p2 = EXP2(CV[2]), p3 = EXP2(CV[3]);                            \
        if (diag_) {                                                         \
            const int lim = (qc*16 + n) - ((CT)*16 + quad*4);                \
            if (0 > lim) p0 = 0.f;                                           \
            if (1 > lim) p1 = 0.f;                                           \
            if (2 > lim) p2 = 0.f;                                           \
            if (3 > lim) p3 = 0.f;                                           \
        }                                                                    \
        p0 = truncbf(p0); p1 = truncbf(p1);                                  \
        p2 = truncbf(p2); p3 = truncbf(p3);                                  \
        ls += (p0 + p1) + (p2 + p3);                                         \
        pb[CP].u[(SL)*2]     = permpack(p0, p1);                             \
        pb[CP].u[(SL)*2 + 1] = permpack(p2, p3);                             \
    }

#define TILE_BODY(KF, PRE, TN, TT)                                           \
  {                                                                          \
    const bool diag_ = ((TT) == qt);                                         \
    _Pragma("unroll")                                                        \
    for (int qc = 0; qc < 4; ++qc) {                                         \
        union { unsigned u[4]; short8 v; } pb[2];                            \
        float ls = 0.f;                                                      \
        _Pragma("unroll")                                                    \
        for (int cp = 0; cp < 2; ++cp) {                                     \
            fragC c0, c1;                                                    \
            __builtin_amdgcn_s_setprio(1);                                   \
            {                                                                \
                fragC z = {0.f,0.f,0.f,0.f};                                 \
                z = MFMA32(KF[cp*2][0], qf[qc][0], z);                       \
                z = MFMA32(KF[cp*2][1], qf[qc][1], z);                       \
                c0 = z;                                                      \
            }                                                                \
            {                                                                \
                fragC z = {0.f,0.f,0.f,0.f};                                 \
                z = MFMA32(KF[cp*2+1][0], qf[qc][0], z);                     \
                z = MFMA32(KF[cp*2+1][1], qf[qc][1], z);                     \
                c1 = z;                                                      \
            }                                                                \
            __builtin_amdgcn_s_setprio(0);                                   \
            SMAX(c0, cp*2,     cp, 0)                                        \
            SMAX(c1, cp*2 + 1, cp, 1)                                        \
        }                                                                    \
        lsc[qc] += ls;                                                       \
        if (qc == 3 && (PRE)) { LOADK(KF, TN) }                              \
        __builtin_amdgcn_s_setprio(1);                                       \
        _Pragma("unroll")                                                    \
        for (int pv = 0; pv < 2; ++pv) {                                     \
            _Pragma("unroll")                                                \
            for (int dt = 0; dt < 4; ++dt)                                   \
                o[qc][dt] = MFMA32(vv[dt][pv], pb[pv].v, o[qc][dt]);         \
        }                                                                    \
        __builtin_amdgcn_s_setprio(0);                                       \
    }                                                                        \
    if ((TT) + 4 < nt) { LOADV((TT) + 4) }                                   \
  }

__global__ __launch_bounds__(256, 2) void attn_kernel(
    const unsigned short* __restrict__ q, const unsigned short* __restrict__ k,
    const unsigned short* __restrict__ vt, unsigned short* __restrict__ aout)
{
    __shared__ fragC Os[4][4][4][64];            // [w][qc][dt][lane] = 64KB
    __shared__ float Ls[4][4][16];               // [w][qc][n]

    const int id = blockIdx.x;
    const int xc = id & 7, p = id >> 3;
    const int jj = p & 3, s = p >> 2, g = s & 7, r2 = s >> 3;
    const int bh = xc*4 + jj;
    const int qt = (r2 == 0) ? 31 - g : (r2 == 1) ? g : (r2 == 2) ? 23 - g : 8 + g;

    const int b   = bh >> 4, h = bh & 15;
    const int tid = threadIdx.x;
    const int w = tid >> 6, lane = tid & 63;
    const int n = lane & 15, quad = lane >> 4;

    // Q fragments for all 4 query columns (tiled layout, pre-scaled)
    short8 qf[4][2];
    #pragma unroll
    for (int qc = 0; qc < 4; ++qc) {
        const unsigned short* qb = &q[((size_t)bh*128 + qt*4 + qc)*1024 + n*8];
        qf[qc][0] = *(const short8*)&qb[quad*128];
        qf[qc][1] = *(const short8*)&qb[(4 + quad)*128];
    }

    fragC o[4][4];                               // [qc][dt], O^T partials
    #pragma unroll
    for (int qc = 0; qc < 4; ++qc)
        #pragma unroll
        for (int dt = 0; dt < 4; ++dt) o[qc][dt] = (fragC){0.f,0.f,0.f,0.f};
    float lsc[4] = {0.f, 0.f, 0.f, 0.f};         // per-lane l partials

    const unsigned short* kg = &k[(size_t)bh*131072 + lane*8];
    const unsigned short* vg = &vt[(size_t)bh*131072 + lane*8];
    const int nt = qt + 1;

    short8 kfA[4][2], kfB[4][2];                 // K ping-pong, 64 VGPRs
    short8 vv[4][2];                             // V tile (paired), 32 VGPRs

    int t = w;
    int ntw = (nt > w) ? ((nt - w + 3) >> 2) : 0;    // tiles for this wave
    if (ntw > 0) {                                   // prologue: V(t), K(t), K(t+4)
        LOADV(t)
        LOADK(kfA, t)
        if (ntw > 1) { LOADK(kfB, t + 4) }
    }
    int i = 0;
    while (i + 2 <= ntw) {
        TILE_BODY(kfA, (i + 2 < ntw), t + 8,  t)
        TILE_BODY(kfB, (i + 3 < ntw), t + 12, t + 4)
        t += 8; i += 2;
    }
    if (i < ntw) { TILE_BODY(kfA, false, 0, t) }

    // cross-quad l reduce: lanes {n, n+16, n+32, n+48} hold key-partials
    #pragma unroll
    for (int qc = 0; qc < 4; ++qc) {
        lsc[qc] += __shfl_xor(lsc[qc], 16);
        lsc[qc] += __shfl_xor(lsc[qc], 32);
    }

    // ---- cross-wave combine (the only barrier) ----
    #pragma unroll
    for (int qc = 0; qc < 4; ++qc) {
        #pragma unroll
        for (int dt = 0; dt < 4; ++dt)
            Os[w][qc][dt][lane] = o[qc][dt];
        if (quad == 0) Ls[w][qc][n] = lsc[qc];
    }
    __syncthreads();

    // wave w owns query column qc = w
    const float lsum = Ls[0][w][n] + Ls[1][w][n] + Ls[2][w][n] + Ls[3][w][n];
    const float inv = 1.0f / lsum;
    const int q0 = qt*64 + w*16;
    unsigned short* dp = &aout[((size_t)b*T_ + q0 + n)*D_ + h*DK + quad*4];
    #pragma unroll
    for (int dt = 0; dt < 4; ++dt) {
        fragC sum = Os[0][w][dt][lane] + Os[1][w][dt][lane]
                  + Os[2][w][dt][lane] + Os[3][w][dt][lane];
        *(uint2*)(dp + dt*16) =
            make_uint2(pack2bf(sum[0]*inv, sum[1]*inv),
                       pack2bf(sum[2]*inv, sum[3]*inv));
    }
}

// ---------------------------------------------------------------------------
// Kernel 3: out = A @ Wb^T + bp.  (R5 build verbatim: 64x128 tiles, grid 512,
// LDS 48KB dbuf, launch_bounds(256,3), XCD-chunked m-rows.)
// ---------------------------------------------------------------------------
__global__ __launch_bounds__(256, 3) void proj_kernel(
    const unsigned short* __restrict__ A, const unsigned short* __restrict__ Wb,
    const float* __restrict__ bp, float* __restrict__ out)
{
    __shared__ unsigned short As[2][64*64];
    __shared__ unsigned short Bs[2][128*64];

    const int id = blockIdx.x;                   // 512 blocks
    const int xcd = id & 7, idx = id >> 3;
    const int m0 = (xcd*8 + (idx & 7)) * 64;
    const int n0 = (idx >> 3) * 128;
    const int tid = threadIdx.x;
    const int wave = tid >> 6, lane = tid & 63;
    const int wm = wave & 1, wn = wave >> 1;
    const int n = lane & 15, quad = lane >> 4;

    const int arow = tid >> 3, acol = (tid & 7) * 8;
    const unsigned short* ag = &A [(size_t)(m0 + arow)*1024 + acol];
    const unsigned short* bg = &Wb[(size_t)(n0 + arow)*1024 + acol];

    fragC acc[2][4];
    #pragma unroll
    for (int i = 0; i < 2; ++i)
        #pragma unroll
        for (int j = 0; j < 4; ++j) acc[i][j] = (fragC){0.f,0.f,0.f,0.f};

    auto stage = [&](int bu, int kt) {
        #pragma unroll
        for (int i2 = 0; i2 < 2; ++i2)
            gload_lds16(ag + (size_t)i2*32*1024 + kt*64, &As[bu][i2*2048 + tid*8]);
        #pragma unroll
        for (int j2 = 0; j2 < 4; ++j2)
            gload_lds16(bg + (size_t)j2*32*1024 + kt*64, &Bs[bu][j2*2048 + tid*8]);
    };

    stage(0, 0);
    for (int kt = 0; kt < 16; ++kt) {
        __syncthreads();                         // drains buf[kt&1] gloads
        if (kt < 15) stage((kt + 1) & 1, kt + 1);
        const unsigned short* Ab = As[kt & 1];
        const unsigned short* Bb = Bs[kt & 1];
        #pragma unroll
        for (int kk = 0; kk < 2; ++kk) {
            short8 af[2], bf[4];
            #pragma unroll
            for (int i = 0; i < 2; ++i)
                af[i] = *(const short8*)&Ab[(wm*32 + i*16 + n)*64 + kk*32 + quad*8];
            #pragma unroll
            for (int j = 0; j < 4; ++j)
                bf[j] = *(const short8*)&Bb[(wn*64 + j*16 + n)*64 + kk*32 + quad*8];
            #pragma unroll
            for (int i = 0; i < 2; ++i)
                #pragma unroll
                for (int j = 0; j < 4; ++j)
                    acc[i][j] = MFMA32(af[i], bf[j], acc[i][j]);
        }
    }

    #pragma unroll
    for (int i = 0; i < 2; ++i) {
        #pragma unroll
        for (int r = 0; r < 4; ++r) {
            const int m = m0 + wm*32 + i*16 + quad*4 + r;
            #pragma unroll
            for (int j = 0; j < 4; ++j) {
                const int col = n0 + wn*64 + j*16 + n;
                out[(size_t)m*1024 + col] = acc[i][j][r] + bp[col];
            }
        }
    }
}

// ---------------------------------------------------------------------------
extern "C" void kernel_launch(void* const* d_in, const int* in_sizes, int n_in,
                              void* d_out, int out_size, void* d_ws, size_t ws_size,
                              hipStream_t stream)
{
    const float* x  = (const float*)d_in[0];
    const float* Wq = (const float*)d_in[1];
    const float* Wk = (const float*)d_in[2];
    const float* Wv = (const float*)d_in[3];
    const float* Wp = (const float*)d_in[4];
    const float* bp = (const float*)d_in[5];
    float* out = (float*)d_out;

    const size_t per = (size_t)BH_ * T_ * DK;        // 4,194,304 elements
    unsigned short* qws   = (unsigned short*)d_ws;   // bf16, tiled, pre-scaled
    unsigned short* kws   = qws + per;               // bf16, tiled
    unsigned short* vtws  = kws + per;               // bf16, vt3 layout
    unsigned short* aws   = vtws + per;              // [B*T, D] bf16
    unsigned short* wbws  = aws + per;               // Wp bf16 [1024*1024]

    qkv_kernel<<<dim3(BH_, T_/128), 256, 0, stream>>>(x, Wq, Wk, Wv, Wp, wbws,
                                                      qws, kws, vtws);
    attn_kernel<<<dim3(1024), 256, 0, stream>>>(qws, kws, vtws, aws);
    proj_kernel<<<dim3(512), 256, 0, stream>>>(aws, wbws, bp, out);
}

// Round 10
// 130.212 us; speedup vs baseline: 1.7409x; 1.7409x over previous
//
#include <hip/hip_runtime.h>
#include <math.h>

#define B_ 2
#define T_ 2048
#define D_ 1024
#define H_ 16
#define DK 64
#define BH_ (B_*H_)

typedef __attribute__((ext_vector_type(8))) short short8;   // 8 bf16 = 4 VGPRs
typedef __attribute__((ext_vector_type(4))) float fragC;    // MFMA C/D

#define MFMA32(A,B,C) __builtin_amdgcn_mfma_f32_16x16x32_bf16((A),(B),(C),0,0,0)

#if defined(__HIP_DEVICE_COMPILE__) && __has_builtin(__builtin_amdgcn_exp2f)
#define EXP2 __builtin_amdgcn_exp2f
#else
#define EXP2 exp2f
#endif

__device__ __forceinline__ unsigned short f2bf(float x) {
    union { float f; unsigned u; } c; c.f = x;
    unsigned r = c.u + 0x7fff + ((c.u >> 16) & 1);   // RNE
    return (unsigned short)(r >> 16);
}

__device__ __forceinline__ unsigned pack2bf(float a, float b) {
    return (unsigned)f2bf(a) | ((unsigned)f2bf(b) << 16);
}

// truncating bf16 pair-pack in ONE op: bytes [a.2,a.3,b.2,b.3]
__device__ __forceinline__ unsigned permpack(float a, float b) {
    union { float f; unsigned u; } ca, cb; ca.f = a; cb.f = b;
    return __builtin_amdgcn_perm(cb.u, ca.u, 0x07060302);
}

// truncate float to bf16-representable value (matches permpack semantics)
__device__ __forceinline__ float truncbf(float x) {
    union { float f; unsigned u; } c; c.f = x;
    c.u &= 0xffff0000u;
    return c.f;
}

__device__ __forceinline__ short8 packbf8(float4 a, float4 b) {
    union { short8 v; unsigned u[4]; } r;
    r.u[0] = pack2bf(a.x, a.y); r.u[1] = pack2bf(a.z, a.w);
    r.u[2] = pack2bf(b.x, b.y); r.u[3] = pack2bf(b.z, b.w);
    return r.v;
}

// async global->LDS, 16B per lane
__device__ __forceinline__ void gload_lds16(const void* g, void* l) {
    __builtin_amdgcn_global_load_lds(
        (const __attribute__((address_space(1))) unsigned int*)g,
        (__attribute__((address_space(3))) unsigned int*)l, 16, 0, 0);
}

// ---------------------------------------------------------------------------
// Kernel 1: MFMA QKV projection + in-kernel weight conversion.
// Each block converts its head's 3x64x64 Wqkv fp32 -> bf16 straight into LDS
// and a 2048-float slice of Wp as a side job (512 blocks cover Wp exactly).
// q (pre-scaled by 0.125*log2e), k: tiled [bh][t16][dblk(8)][t%16][8].
// v: vt3 layout [bh][kt(64-key)][dt(4)][pair(2)][lane(64)][8] -> stores are
// dense uint4 per lane; attn loads one dwordx4 = keys pv*32+(j>>2)*16+quad*4+j
// per lane — the SAME lane->k map the packed-P short8 has (MFMA32 PV).
// grid (BH, T/128), block 256 = 4 waves, wave owns 32 t-rows.
// ---------------------------------------------------------------------------
__global__ __launch_bounds__(256) void qkv_kernel(
    const float* __restrict__ x,
    const float* __restrict__ Wq, const float* __restrict__ Wk,
    const float* __restrict__ Wv, const float* __restrict__ Wp,
    unsigned short* __restrict__ Wb,
    unsigned short* __restrict__ q, unsigned short* __restrict__ k,
    unsigned short* __restrict__ vt)
{
    __shared__ unsigned short Wl[3*64*64];       // [mat][out][d]

    const int bh = blockIdx.x;
    const int b  = bh >> 4, h = bh & 15;
    const int t0 = blockIdx.y * 128;
    const int tid = threadIdx.x;
    const int wave = tid >> 6, lane = tid & 63;
    const int n = lane & 15, quad = lane >> 4;

    // Wp side job: block L converts floats [L*2048, L*2048+2048)
    {
        const int L = bh + (blockIdx.y << 5);                 // 0..511
        const float* src = Wp + (size_t)L*2048 + tid*8;
        float4 a = *(const float4*)src;
        float4 b2 = *(const float4*)(src + 4);
        *(uint4*)(Wb + (size_t)L*2048 + tid*8) =
            make_uint4(pack2bf(a.x, a.y), pack2bf(a.z, a.w),
                       pack2bf(b2.x, b2.y), pack2bf(b2.z, b2.w));
    }

    // convert this head's 3x64x64 fp32 weights -> LDS bf16
    #pragma unroll
    for (int mat = 0; mat < 3; ++mat) {
        const float* ws = ((mat == 0) ? Wq : (mat == 1) ? Wk : Wv)
                          + (size_t)h * 4096;
        #pragma unroll
        for (int j = 0; j < 2; ++j) {
            const int e = (j*256 + tid) * 8;
            float4 a = *(const float4*)&ws[e];
            float4 b2 = *(const float4*)&ws[e + 4];
            *(uint4*)&Wl[mat*4096 + e] =
                make_uint4(pack2bf(a.x, a.y), pack2bf(a.z, a.w),
                           pack2bf(b2.x, b2.y), pack2bf(b2.z, b2.w));
        }
    }

    // x fragments: fp32 loads + RNE pack (lane n <-> t = tw + rt*16 + n)
    const int tw = t0 + wave*32;
    short8 xf[2][2];
    #pragma unroll
    for (int rt = 0; rt < 2; ++rt) {
        const float* xr = &x[((size_t)b*T_ + tw + rt*16 + n)*D_ + h*DK];
        float4 a0 = *(const float4*)&xr[quad*8];
        float4 a1 = *(const float4*)&xr[quad*8 + 4];
        xf[rt][0] = packbf8(a0, a1);
        float4 b0 = *(const float4*)&xr[32 + quad*8];
        float4 b1 = *(const float4*)&xr[32 + quad*8 + 4];
        xf[rt][1] = packbf8(b0, b1);
    }
    __syncthreads();

    const float qsc = 0.125f * 1.44269504088896340736f;
    const int tb0 = blockIdx.y*8 + wave*2;       // tiled t16-block base
    #pragma unroll
    for (int mat = 0; mat < 3; ++mat) {
        const int wbase = mat * 4096;
        #pragma unroll
        for (int ct = 0; ct < 4; ++ct) {
            short8 wf0 = *(const short8*)&Wl[wbase + (ct*16 + n)*64 + quad*8];
            short8 wf1 = *(const short8*)&Wl[wbase + (ct*16 + n)*64 + 32 + quad*8];
            if (mat < 2) {
                #pragma unroll
                for (int rt = 0; rt < 2; ++rt) {
                    fragC z = {0.f,0.f,0.f,0.f};
                    // q^T/k^T: C col = t = n, row = out = ct*16+quad*4+r
                    z = MFMA32(wf0, xf[rt][0], z);
                    z = MFMA32(wf1, xf[rt][1], z);
                    if (mat == 0) {
                        z[0] *= qsc; z[1] *= qsc; z[2] *= qsc; z[3] *= qsc;
                    }
                    unsigned short* dstg = (mat == 0) ? q : k;
                    unsigned short* dp = &dstg[((size_t)bh*128 + tb0 + rt)*1024
                                               + (ct*2 + (quad>>1))*128 + n*8 + (quad&1)*4];
                    *(uint2*)dp = make_uint2(pack2bf(z[0], z[1]), pack2bf(z[2], z[3]));
                }
            } else {
                // v: C col = d = ct*16+n, row = t = quad*4+r; rt pair -> one uint4
                uint4 pv4;
                {
                    fragC z = {0.f,0.f,0.f,0.f};
                    z = MFMA32(xf[0][0], wf0, z);
                    z = MFMA32(xf[0][1], wf1, z);
                    pv4.x = pack2bf(z[0], z[1]); pv4.y = pack2bf(z[2], z[3]);
                }
                {
                    fragC z = {0.f,0.f,0.f,0.f};
                    z = MFMA32(xf[1][0], wf0, z);
                    z = MFMA32(xf[1][1], wf1, z);
                    pv4.z = pack2bf(z[0], z[1]); pv4.w = pack2bf(z[2], z[3]);
                }
                const int ktv = tw >> 6, pv = (tw >> 5) & 1;
                unsigned short* dp = &vt[(size_t)bh*131072 + ktv*4096
                                         + ct*1024 + pv*512 + lane*8];
                *(uint4*)dp = pv4;
            }
        }
    }
}

// ---------------------------------------------------------------------------
// Kernel 2: causal flash attention — R10: byte-exact revert to the R5 build
// (measured 131.3 µs, session best).  R7/R8/R9 post-mortems: this body is AT
// the 256-VGPR capacity of launch_bounds(256,2); any +32-reg addition (K
// double-buffer in regs, however expressed) or tighter cap spills to scratch
// (240-280 MB writes, 4-5x regression).  Structure frozen:
//  - per-qc immediate consume: S(qc) -> softmax(qc) -> PV(qc)
//  - l summed in-lane on bf16-truncated p (identical to summing packed P),
//    cross-quad reduce via 2x shfl_xor at loop end
//  - exp2 via __builtin_amdgcn_exp2f
// Block = (bh, qt) = 64 queries; 4 waves split KEY tiles (kt = w, w+4, ..):
// serial path 8 tiles, zero per-tile barriers, K/V loaded global->VGPR.
// K(t+4) issued right after its last S read (qc3); V(t+4) at loop end.
// One barrier per block: 64KB-LDS cross-wave O/l combine.
// Grid swizzle: XCD id&7 owns bh 4x..4x+3; qt map {31-g, g, 23-g, 8+g}.
// ---------------------------------------------------------------------------
__global__ __launch_bounds__(256, 2) void attn_kernel(
    const unsigned short* __restrict__ q, const unsigned short* __restrict__ k,
    const unsigned short* __restrict__ vt, unsigned short* __restrict__ aout)
{
    __shared__ fragC Os[4][4][4][64];            // [w][qc][dt][lane] = 64KB
    __shared__ float Ls[4][4][16];               // [w][qc][n]

    const int id = blockIdx.x;
    const int xc = id & 7, p = id >> 3;
    const int jj = p & 3, s = p >> 2, g = s & 7, r = s >> 3;
    const int bh = xc*4 + jj;
    const int qt = (r == 0) ? 31 - g : (r == 1) ? g : (r == 2) ? 23 - g : 8 + g;

    const int b   = bh >> 4, h = bh & 15;
    const int tid = threadIdx.x;
    const int w = tid >> 6, lane = tid & 63;
    const int n = lane & 15, quad = lane >> 4;

    // Q fragments for all 4 query columns (tiled layout, pre-scaled)
    short8 qf[4][2];
    #pragma unroll
    for (int qc = 0; qc < 4; ++qc) {
        const unsigned short* qb = &q[((size_t)bh*128 + qt*4 + qc)*1024 + n*8];
        qf[qc][0] = *(const short8*)&qb[quad*128];
        qf[qc][1] = *(const short8*)&qb[(4 + quad)*128];
    }

    fragC o[4][4];                               // [qc][dt], O^T partials
    #pragma unroll
    for (int qc = 0; qc < 4; ++qc)
        #pragma unroll
        for (int dt = 0; dt < 4; ++dt) o[qc][dt] = (fragC){0.f,0.f,0.f,0.f};
    float lsc[4] = {0.f, 0.f, 0.f, 0.f};         // per-lane l partials

    const unsigned short* kg = &k[(size_t)bh*131072 + lane*8];
    const unsigned short* vg = &vt[(size_t)bh*131072 + lane*8];
    const int nt = qt + 1;

    short8 kf[4][2];                             // K tile, 32 VGPRs
    short8 vv[4][2];                             // V tile (paired), 32 VGPRs

    int t = w;
    if (t < nt) {                                // prologue K+V load
        #pragma unroll
        for (int ct = 0; ct < 4; ++ct) {
            kf[ct][0] = *(const short8*)&kg[t*4096 + ct*1024];
            kf[ct][1] = *(const short8*)&kg[t*4096 + ct*1024 + 512];
        }
        #pragma unroll
        for (int dt = 0; dt < 4; ++dt) {
            vv[dt][0] = *(const short8*)&vg[t*4096 + dt*1024];
            vv[dt][1] = *(const short8*)&vg[t*4096 + dt*1024 + 512];
        }
    }

    for (; t < nt; t += 4) {
        const bool diag = (t == qt);
        #pragma unroll
        for (int qc = 0; qc < 4; ++qc) {
            // ---- S(qc): 8 MFMA32 ----
            fragC c[4];
            __builtin_amdgcn_s_setprio(1);
            #pragma unroll
            for (int ct = 0; ct < 4; ++ct) {
                fragC z = {0.f,0.f,0.f,0.f};
                z = MFMA32(kf[ct][0], qf[qc][0], z);
                z = MFMA32(kf[ct][1], qf[qc][1], z);
                c[ct] = z;
            }
            __builtin_amdgcn_s_setprio(0);

            // kf fully read after qc3's S -> issue K(t+4) NOW
            if (qc == 3 && t + 4 < nt) {
                #pragma unroll
                for (int ct = 0; ct < 4; ++ct) {
                    kf[ct][0] = *(const short8*)&kg[(t+4)*4096 + ct*1024];
                    kf[ct][1] = *(const short8*)&kg[(t+4)*4096 + ct*1024 + 512];
                }
            }

            // ---- softmax(qc): exp2, mask, truncate, l-sum, pack ----
            union { unsigned u[4]; short8 v; } pb[2];
            float ls = 0.f;
            #pragma unroll
            for (int ct = 0; ct < 4; ++ct) {
                float p0 = EXP2(c[ct][0]), p1 = EXP2(c[ct][1]);
                float p2 = EXP2(c[ct][2]), p3 = EXP2(c[ct][3]);
                if (diag) {
                    const int lim = (qc*16 + n) - (ct*16 + quad*4);
                    if (0 > lim) p0 = 0.f;
                    if (1 > lim) p1 = 0.f;
                    if (2 > lim) p2 = 0.f;
                    if (3 > lim) p3 = 0.f;
                }
                p0 = truncbf(p0); p1 = truncbf(p1);
                p2 = truncbf(p2); p3 = truncbf(p3);
                ls += (p0 + p1) + (p2 + p3);
                pb[ct >> 1].u[(ct & 1)*2]     = permpack(p0, p1);
                pb[ct >> 1].u[(ct & 1)*2 + 1] = permpack(p2, p3);
            }
            lsc[qc] += ls;

            // ---- PV(qc): 8 MFMA32 (pb lane->k map == vv's) ----
            __builtin_amdgcn_s_setprio(1);
            #pragma unroll
            for (int pv = 0; pv < 2; ++pv) {
                #pragma unroll
                for (int dt = 0; dt < 4; ++dt)
                    o[qc][dt] = MFMA32(vv[dt][pv], pb[pv].v, o[qc][dt]);
            }
            __builtin_amdgcn_s_setprio(0);
        }

        // vv fully read -> issue V(t+4); full next-tile S+softmax of flight
        if (t + 4 < nt) {
            #pragma unroll
            for (int dt = 0; dt < 4; ++dt) {
                vv[dt][0] = *(const short8*)&vg[(t+4)*4096 + dt*1024];
                vv[dt][1] = *(const short8*)&vg[(t+4)*4096 + dt*1024 + 512];
            }
        }
    }

    // cross-quad l reduce: lanes {n, n+16, n+32, n+48} hold key-partials
    #pragma unroll
    for (int qc = 0; qc < 4; ++qc) {
        lsc[qc] += __shfl_xor(lsc[qc], 16);
        lsc[qc] += __shfl_xor(lsc[qc], 32);
    }

    // ---- cross-wave combine (the only barrier) ----
    #pragma unroll
    for (int qc = 0; qc < 4; ++qc) {
        #pragma unroll
        for (int dt = 0; dt < 4; ++dt)
            Os[w][qc][dt][lane] = o[qc][dt];
        if (quad == 0) Ls[w][qc][n] = lsc[qc];
    }
    __syncthreads();

    // wave w owns query column qc = w
    const float lsum = Ls[0][w][n] + Ls[1][w][n] + Ls[2][w][n] + Ls[3][w][n];
    const float inv = 1.0f / lsum;
    const int q0 = qt*64 + w*16;
    unsigned short* dp = &aout[((size_t)b*T_ + q0 + n)*D_ + h*DK + quad*4];
    #pragma unroll
    for (int dt = 0; dt < 4; ++dt) {
        fragC sum = Os[0][w][dt][lane] + Os[1][w][dt][lane]
                  + Os[2][w][dt][lane] + Os[3][w][dt][lane];
        *(uint2*)(dp + dt*16) =
            make_uint2(pack2bf(sum[0]*inv, sum[1]*inv),
                       pack2bf(sum[2]*inv, sum[3]*inv));
    }
}

// ---------------------------------------------------------------------------
// Kernel 3: out = A @ Wb^T + bp.   A:[4096,1024] bf16, Wb:[1024,1024] bf16 (B^T)
// 64x128 tiles (grid 512, LDS 48KB dbuf, launch_bounds(256,3)) ->
// 3 blocks/CU = 12 waves/CU so per-K-step barrier drains overlap across
// blocks.  XCD-chunked: XCD x owns m-rows [512x, 512x+512).
// ---------------------------------------------------------------------------
__global__ __launch_bounds__(256, 3) void proj_kernel(
    const unsigned short* __restrict__ A, const unsigned short* __restrict__ Wb,
    const float* __restrict__ bp, float* __restrict__ out)
{
    __shared__ unsigned short As[2][64*64];
    __shared__ unsigned short Bs[2][128*64];

    const int id = blockIdx.x;                   // 512 blocks
    const int xcd = id & 7, idx = id >> 3;
    const int m0 = (xcd*8 + (idx & 7)) * 64;
    const int n0 = (idx >> 3) * 128;
    const int tid = threadIdx.x;
    const int wave = tid >> 6, lane = tid & 63;
    const int wm = wave & 1, wn = wave >> 1;
    const int n = lane & 15, quad = lane >> 4;

    const int arow = tid >> 3, acol = (tid & 7) * 8;
    const unsigned short* ag = &A [(size_t)(m0 + arow)*1024 + acol];
    const unsigned short* bg = &Wb[(size_t)(n0 + arow)*1024 + acol];

    fragC acc[2][4];
    #pragma unroll
    for (int i = 0; i < 2; ++i)
        #pragma unroll
        for (int j = 0; j < 4; ++j) acc[i][j] = (fragC){0.f,0.f,0.f,0.f};

    auto stage = [&](int bu, int kt) {
        #pragma unroll
        for (int i2 = 0; i2 < 2; ++i2)
            gload_lds16(ag + (size_t)i2*32*1024 + kt*64, &As[bu][i2*2048 + tid*8]);
        #pragma unroll
        for (int j2 = 0; j2 < 4; ++j2)
            gload_lds16(bg + (size_t)j2*32*1024 + kt*64, &Bs[bu][j2*2048 + tid*8]);
    };

    stage(0, 0);
    for (int kt = 0; kt < 16; ++kt) {
        __syncthreads();                         // drains buf[kt&1] gloads
        if (kt < 15) stage((kt + 1) & 1, kt + 1);
        const unsigned short* Ab = As[kt & 1];
        const unsigned short* Bb = Bs[kt & 1];
        #pragma unroll
        for (int kk = 0; kk < 2; ++kk) {
            short8 af[2], bf[4];
            #pragma unroll
            for (int i = 0; i < 2; ++i)
                af[i] = *(const short8*)&Ab[(wm*32 + i*16 + n)*64 + kk*32 + quad*8];
            #pragma unroll
            for (int j = 0; j < 4; ++j)
                bf[j] = *(const short8*)&Bb[(wn*64 + j*16 + n)*64 + kk*32 + quad*8];
            #pragma unroll
            for (int i = 0; i < 2; ++i)
                #pragma unroll
                for (int j = 0; j < 4; ++j)
                    acc[i][j] = MFMA32(af[i], bf[j], acc[i][j]);
        }
    }

    #pragma unroll
    for (int i = 0; i < 2; ++i) {
        #pragma unroll
        for (int r = 0; r < 4; ++r) {
            const int m = m0 + wm*32 + i*16 + quad*4 + r;
            #pragma unroll
            for (int j = 0; j < 4; ++j) {
                const int col = n0 + wn*64 + j*16 + n;
                out[(size_t)m*1024 + col] = acc[i][j][r] + bp[col];
            }
        }
    }
}

// ---------------------------------------------------------------------------
extern "C" void kernel_launch(void* const* d_in, const int* in_sizes, int n_in,
                              void* d_out, int out_size, void* d_ws, size_t ws_size,
                              hipStream_t stream)
{
    const float* x  = (const float*)d_in[0];
    const float* Wq = (const float*)d_in[1];
    const float* Wk = (const float*)d_in[2];
    const float* Wv = (const float*)d_in[3];
    const float* Wp = (const float*)d_in[4];
    const float* bp = (const float*)d_in[5];
    float* out = (float*)d_out;

    const size_t per = (size_t)BH_ * T_ * DK;        // 4,194,304 elements
    unsigned short* qws   = (unsigned short*)d_ws;   // bf16, tiled, pre-scaled
    unsigned short* kws   = qws + per;               // bf16, tiled
    unsigned short* vtws  = kws + per;               // bf16, vt3 layout
    unsigned short* aws   = vtws + per;              // [B*T, D] bf16
    unsigned short* wbws  = aws + per;               // Wp bf16 [1024*1024]

    qkv_kernel<<<dim3(BH_, T_/128), 256, 0, stream>>>(x, Wq, Wk, Wv, Wp, wbws,
                                                      qws, kws, vtws);
    attn_kernel<<<dim3(1024), 256, 0, stream>>>(qws, kws, vtws, aws);
    proj_kernel<<<dim3(512), 256, 0, stream>>>(aws, wbws, bp, out);
}